// Round 2
// baseline (2047.324 us; speedup 1.0000x reference)
//
#include <hip/hip_runtime.h>

#define S_LEN 2048
#define B_SZ  16
#define F_DIM 256
#define NROWS (S_LEN * B_SZ)   // 32768

typedef unsigned short ushort_t;
typedef unsigned int   uint_t;

__device__ __forceinline__ ushort_t f2bf(float f) {
    uint_t x = __float_as_uint(f);
    uint_t r = x + 0x7fffu + ((x >> 16) & 1u);
    return (ushort_t)(r >> 16);
}
__device__ __forceinline__ float bf_lo(uint_t u) { return __uint_as_float(u << 16); }
__device__ __forceinline__ float bf_hi(uint_t u) { return __uint_as_float(u & 0xffff0000u); }

// ---------------------------------------------------------------------------
// Kernel 1: QKV projection.  Y[r,c] = sum_f X[r,f] * W[c,f] + bias[c]
// X: [32768, 256] fp32 (x is [S,B,F], row r = s*B+b).  Output stored bf16.
// ---------------------------------------------------------------------------
__global__ __launch_bounds__(256) void qkv_proj_kernel(
    const float* __restrict__ x,
    const float* __restrict__ Wq, const float* __restrict__ bq,
    const float* __restrict__ Wk, const float* __restrict__ bk,
    const float* __restrict__ Wv, const float* __restrict__ bv,
    ushort_t* __restrict__ Qd, ushort_t* __restrict__ Kd, ushort_t* __restrict__ Vd)
{
    const int bm   = blockIdx.x;          // 0..511
    const int by   = blockIdx.y;          // 0..11
    const int mat  = by >> 2;             // 0:Q 1:K 2:V
    const int col0 = (by & 3) * 64;

    const float* W    = (mat == 0) ? Wq : (mat == 1) ? Wk : Wv;
    const float* bias = (mat == 0) ? bq : (mat == 1) ? bk : bv;
    ushort_t*    Y    = (mat == 0) ? Qd : (mat == 1) ? Kd : Vd;

    __shared__ float Xs[64][65];
    __shared__ float Ws[64][65];

    const int tid = threadIdx.x;
    const int ty  = tid >> 4;             // 0..15
    const int tx  = tid & 15;             // 0..15
    const int ty4 = ty * 4, tx4 = tx * 4;
    const int r0  = bm * 64;

    float acc[4][4] = {};

    for (int k0 = 0; k0 < F_DIM; k0 += 64) {
        {
            const int rr = tid >> 4;            // 0..15
            const int f4 = (tid & 15) * 4;      // 0..60
            #pragma unroll
            for (int p = 0; p < 4; ++p) {
                const int row = rr + p * 16;
                float4 xv = *reinterpret_cast<const float4*>(&x[(size_t)(r0 + row) * F_DIM + k0 + f4]);
                Xs[row][f4 + 0] = xv.x; Xs[row][f4 + 1] = xv.y;
                Xs[row][f4 + 2] = xv.z; Xs[row][f4 + 3] = xv.w;
                float4 wv = *reinterpret_cast<const float4*>(&W[(size_t)(col0 + row) * F_DIM + k0 + f4]);
                Ws[row][f4 + 0] = wv.x; Ws[row][f4 + 1] = wv.y;
                Ws[row][f4 + 2] = wv.z; Ws[row][f4 + 3] = wv.w;
            }
        }
        __syncthreads();

        #pragma unroll 4
        for (int f = 0; f < 64; ++f) {
            float a[4], bb[4];
            #pragma unroll
            for (int i = 0; i < 4; ++i) a[i]  = Xs[ty4 + i][f];
            #pragma unroll
            for (int j = 0; j < 4; ++j) bb[j] = Ws[tx4 + j][f];
            #pragma unroll
            for (int i = 0; i < 4; ++i)
                #pragma unroll
                for (int j = 0; j < 4; ++j)
                    acc[i][j] = fmaf(a[i], bb[j], acc[i][j]);
        }
        __syncthreads();
    }

    #pragma unroll
    for (int i = 0; i < 4; ++i) {
        const int r = r0 + ty4 + i;
        const int c0 = col0 + tx4;
        ushort4 u;
        u.x = f2bf(acc[i][0] + bias[c0 + 0]);
        u.y = f2bf(acc[i][1] + bias[c0 + 1]);
        u.z = f2bf(acc[i][2] + bias[c0 + 2]);
        u.w = f2bf(acc[i][3] + bias[c0 + 3]);
        *reinterpret_cast<ushort4*>(&Y[(size_t)r * F_DIM + c0]) = u;
    }
}

// ---------------------------------------------------------------------------
// Kernel 2: flash-style attention, one batch b x 64 query rows per block.
// Q tile resident in LDS (fp32, full 256 feats).  K and V cycle through ONE
// shared chunk buffer [64 rows][64 feats] -- 4 feature-chunks each for the
// score and PV phases.  LDS total: 66.5 + 16.6 + 16.6 = 99.8 KB -> 1 blk/CU.
// ---------------------------------------------------------------------------
__global__ __launch_bounds__(256) void attn_kernel(
    const ushort_t* __restrict__ Qd,
    const ushort_t* __restrict__ Kd,
    const ushort_t* __restrict__ Vd,
    float* __restrict__ out)
{
    const int q0 = blockIdx.x * 64;
    const int b  = blockIdx.y;

    __shared__ float Qs[64][260];   // stride 260: a-reads 2-way banked (free)
    __shared__ float KVs[64][65];   // K chunk, then V chunk (stride 65: 2-way)
    __shared__ float Ps[64][65];

    const int tid = threadIdx.x;
    const int ty  = tid >> 4, tx = tid & 15;
    const int ty4 = ty * 4,  tx4 = tx * 4;

    // ---- load full Q tile (scaled by 1/sqrt(F) = 1/16, exact in fp32) ----
    {
        const int c8 = tid & 31;          // 32 chunks of 8 bf16 -> 256 feats
        const int rr = tid >> 5;          // 0..7
        #pragma unroll
        for (int p = 0; p < 8; ++p) {
            const int row = rr + p * 8;
            const uint4 u = *reinterpret_cast<const uint4*>(
                &Qd[((size_t)(q0 + row) * B_SZ + b) * F_DIM + c8 * 8]);
            Qs[row][c8*8+0] = bf_lo(u.x) * 0.0625f; Qs[row][c8*8+1] = bf_hi(u.x) * 0.0625f;
            Qs[row][c8*8+2] = bf_lo(u.y) * 0.0625f; Qs[row][c8*8+3] = bf_hi(u.y) * 0.0625f;
            Qs[row][c8*8+4] = bf_lo(u.z) * 0.0625f; Qs[row][c8*8+5] = bf_hi(u.z) * 0.0625f;
            Qs[row][c8*8+6] = bf_lo(u.w) * 0.0625f; Qs[row][c8*8+7] = bf_hi(u.w) * 0.0625f;
        }
    }

    float m_run[4], l_run[4], O[4][16];
    #pragma unroll
    for (int i = 0; i < 4; ++i) {
        m_run[i] = -1e30f; l_run[i] = 0.0f;
        #pragma unroll
        for (int c = 0; c < 16; ++c) O[i][c] = 0.0f;
    }
    __syncthreads();   // Q tile visible to all

    for (int t0 = 0; t0 < S_LEN; t0 += 64) {
        // ================= scores: sc = (Q/16) . K^T, chunked over feats ====
        float sc[4][4] = {};
        for (int kc = 0; kc < 4; ++kc) {
            {   // load K chunk [64 rows][64 feats]
                const int c8 = tid & 7;       // 8 chunks of 8 -> 64 feats
                const int rr = tid >> 3;      // 0..31
                #pragma unroll
                for (int p = 0; p < 2; ++p) {
                    const int row = rr + p * 32;
                    const uint4 u = *reinterpret_cast<const uint4*>(
                        &Kd[((size_t)(t0 + row) * B_SZ + b) * F_DIM + kc * 64 + c8 * 8]);
                    KVs[row][c8*8+0] = bf_lo(u.x); KVs[row][c8*8+1] = bf_hi(u.x);
                    KVs[row][c8*8+2] = bf_lo(u.y); KVs[row][c8*8+3] = bf_hi(u.y);
                    KVs[row][c8*8+4] = bf_lo(u.z); KVs[row][c8*8+5] = bf_hi(u.z);
                    KVs[row][c8*8+6] = bf_lo(u.w); KVs[row][c8*8+7] = bf_hi(u.w);
                }
            }
            __syncthreads();
            #pragma unroll 4
            for (int f = 0; f < 64; ++f) {
                float a[4], bb[4];
                #pragma unroll
                for (int i = 0; i < 4; ++i) a[i]  = Qs[ty4 + i][kc * 64 + f];
                #pragma unroll
                for (int j = 0; j < 4; ++j) bb[j] = KVs[tx4 + j][f];
                #pragma unroll
                for (int i = 0; i < 4; ++i)
                    #pragma unroll
                    for (int j = 0; j < 4; ++j)
                        sc[i][j] = fmaf(a[i], bb[j], sc[i][j]);
            }
            __syncthreads();   // before next chunk overwrites KVs
        }

        // ================= online softmax (reduce across 16 tx lanes) =======
        #pragma unroll
        for (int i = 0; i < 4; ++i) {
            float mt = fmaxf(fmaxf(sc[i][0], sc[i][1]), fmaxf(sc[i][2], sc[i][3]));
            mt = fmaxf(mt, __shfl_xor(mt, 1));
            mt = fmaxf(mt, __shfl_xor(mt, 2));
            mt = fmaxf(mt, __shfl_xor(mt, 4));
            mt = fmaxf(mt, __shfl_xor(mt, 8));
            const float mn  = fmaxf(m_run[i], mt);
            const float fac = __expf(m_run[i] - mn);
            m_run[i] = mn;
            float ps = 0.0f;
            #pragma unroll
            for (int j = 0; j < 4; ++j) {
                const float p = __expf(sc[i][j] - mn);
                sc[i][j] = p;
                ps += p;
            }
            ps += __shfl_xor(ps, 1);
            ps += __shfl_xor(ps, 2);
            ps += __shfl_xor(ps, 4);
            ps += __shfl_xor(ps, 8);
            l_run[i] = l_run[i] * fac + ps;
            #pragma unroll
            for (int c = 0; c < 16; ++c) O[i][c] *= fac;
            #pragma unroll
            for (int j = 0; j < 4; ++j) Ps[ty4 + i][tx4 + j] = sc[i][j];
        }
        // (no sync needed here: the sync after the first V-chunk load orders
        //  Ps writes before any Ps reads)

        // ================= PV: O[.][kc*4+m] += P . V, chunked over feats ====
        for (int kc = 0; kc < 4; ++kc) {
            {   // load V chunk [64 rows][64 feats] into the SAME buffer
                const int c8 = tid & 7;
                const int rr = tid >> 3;
                #pragma unroll
                for (int p = 0; p < 2; ++p) {
                    const int row = rr + p * 32;
                    const uint4 u = *reinterpret_cast<const uint4*>(
                        &Vd[((size_t)(t0 + row) * B_SZ + b) * F_DIM + kc * 64 + c8 * 8]);
                    KVs[row][c8*8+0] = bf_lo(u.x); KVs[row][c8*8+1] = bf_hi(u.x);
                    KVs[row][c8*8+2] = bf_lo(u.y); KVs[row][c8*8+3] = bf_hi(u.y);
                    KVs[row][c8*8+4] = bf_lo(u.z); KVs[row][c8*8+5] = bf_hi(u.z);
                    KVs[row][c8*8+6] = bf_lo(u.w); KVs[row][c8*8+7] = bf_hi(u.w);
                }
            }
            __syncthreads();
            #pragma unroll 2
            for (int t = 0; t < 64; ++t) {
                float pa[4], v[4];
                #pragma unroll
                for (int i = 0; i < 4; ++i) pa[i] = Ps[ty4 + i][t];
                #pragma unroll
                for (int m = 0; m < 4; ++m) v[m]  = KVs[t][tx4 + m];
                #pragma unroll
                for (int i = 0; i < 4; ++i)
                    #pragma unroll
                    for (int m = 0; m < 4; ++m)
                        O[i][kc*4+m] = fmaf(pa[i], v[m], O[i][kc*4+m]);
            }
            __syncthreads();   // before next chunk (or next tile's K) overwrites
        }
    }

    // ---- normalize and store: out[(q0+row)*B + b][col], col = kc*64+tx4+m --
    #pragma unroll
    for (int i = 0; i < 4; ++i) {
        const float inv = 1.0f / l_run[i];
        const size_t rbase = ((size_t)(q0 + ty4 + i) * B_SZ + b) * F_DIM;
        #pragma unroll
        for (int kc = 0; kc < 4; ++kc) {
            float4 o;
            o.x = O[i][kc*4+0] * inv; o.y = O[i][kc*4+1] * inv;
            o.z = O[i][kc*4+2] * inv; o.w = O[i][kc*4+3] * inv;
            *reinterpret_cast<float4*>(&out[rbase + kc * 64 + tx4]) = o;
        }
    }
}

extern "C" void kernel_launch(void* const* d_in, const int* in_sizes, int n_in,
                              void* d_out, int out_size, void* d_ws, size_t ws_size,
                              hipStream_t stream) {
    const float* x  = (const float*)d_in[0];
    const float* Wq = (const float*)d_in[1];
    const float* bq = (const float*)d_in[2];
    const float* Wk = (const float*)d_in[3];
    const float* bk = (const float*)d_in[4];
    const float* Wv = (const float*)d_in[5];
    const float* bv = (const float*)d_in[6];
    float* out = (float*)d_out;

    const size_t elems = (size_t)NROWS * F_DIM;     // 8.4M per tensor
    ushort_t* Qd = (ushort_t*)d_ws;
    ushort_t* Kd = Qd + elems;
    ushort_t* Vd = Kd + elems;                       // 50.3 MB of ws total

    hipLaunchKernelGGL(qkv_proj_kernel, dim3(512, 12), dim3(256), 0, stream,
                       x, Wq, bq, Wk, bk, Wv, bv, Qd, Kd, Vd);
    hipLaunchKernelGGL(attn_kernel, dim3(S_LEN / 64, B_SZ), dim3(256), 0, stream,
                       Qd, Kd, Vd, out);
}

// Round 4
// 571.176 us; speedup vs baseline: 3.5844x; 3.5844x over previous
//
#include <hip/hip_runtime.h>

#define S_LEN 2048
#define B_SZ  16
#define F_DIM 256
#define NROWS (S_LEN * B_SZ)   // 32768

typedef unsigned short ushort_t;
typedef unsigned int   uint_t;
typedef __attribute__((ext_vector_type(8))) short bf16x8;
typedef __attribute__((ext_vector_type(4))) float f32x4;

__device__ __forceinline__ ushort_t f2bf(float f) {
    uint_t x = __float_as_uint(f);
    uint_t r = x + 0x7fffu + ((x >> 16) & 1u);
    return (ushort_t)(r >> 16);
}

// ---------------------------------------------------------------------------
// Kernel 1: QKV projection.  Y[r,c] = sum_f X[r,f] * W[c,f] + bias[c]
// Q, K stored row-major [r][f] bf16.  V stored TRANSPOSED: Vt[b][f][s] bf16
// (s = r>>4, b = r&15) so the attention kernel gets contiguous V columns.
// ws usage: exactly 3 x 16.77 MB = 50.33 MB (R2-proven size; R3's 4th
// buffer overflowed ws and corrupted an input -> post-timing divergence).
// ---------------------------------------------------------------------------
__global__ __launch_bounds__(256) void qkv_proj_kernel(
    const float* __restrict__ x,
    const float* __restrict__ Wq, const float* __restrict__ bq,
    const float* __restrict__ Wk, const float* __restrict__ bk,
    const float* __restrict__ Wv, const float* __restrict__ bv,
    ushort_t* __restrict__ Qd, ushort_t* __restrict__ Kd, ushort_t* __restrict__ Vtd)
{
    const int bm   = blockIdx.x;
    const int by   = blockIdx.y;
    const int mat  = by >> 2;
    const int col0 = (by & 3) * 64;

    const float* W    = (mat == 0) ? Wq : (mat == 1) ? Wk : Wv;
    const float* bias = (mat == 0) ? bq : (mat == 1) ? bk : bv;

    __shared__ float Xs[64][65];
    __shared__ float Ws[64][65];

    const int tid = threadIdx.x;
    const int ty  = tid >> 4, tx = tid & 15;
    const int ty4 = ty * 4,  tx4 = tx * 4;
    const int r0  = bm * 64;

    float acc[4][4] = {};

    for (int k0 = 0; k0 < F_DIM; k0 += 64) {
        {
            const int rr = tid >> 4;
            const int f4 = (tid & 15) * 4;
            #pragma unroll
            for (int p = 0; p < 4; ++p) {
                const int row = rr + p * 16;
                float4 xv = *reinterpret_cast<const float4*>(&x[(size_t)(r0 + row) * F_DIM + k0 + f4]);
                Xs[row][f4 + 0] = xv.x; Xs[row][f4 + 1] = xv.y;
                Xs[row][f4 + 2] = xv.z; Xs[row][f4 + 3] = xv.w;
                float4 wv = *reinterpret_cast<const float4*>(&W[(size_t)(col0 + row) * F_DIM + k0 + f4]);
                Ws[row][f4 + 0] = wv.x; Ws[row][f4 + 1] = wv.y;
                Ws[row][f4 + 2] = wv.z; Ws[row][f4 + 3] = wv.w;
            }
        }
        __syncthreads();
        #pragma unroll 4
        for (int f = 0; f < 64; ++f) {
            float a[4], bb[4];
            #pragma unroll
            for (int i = 0; i < 4; ++i) a[i]  = Xs[ty4 + i][f];
            #pragma unroll
            for (int j = 0; j < 4; ++j) bb[j] = Ws[tx4 + j][f];
            #pragma unroll
            for (int i = 0; i < 4; ++i)
                #pragma unroll
                for (int j = 0; j < 4; ++j)
                    acc[i][j] = fmaf(a[i], bb[j], acc[i][j]);
        }
        __syncthreads();
    }

    if (mat < 2) {
        ushort_t* Y = (mat == 0) ? Qd : Kd;
        #pragma unroll
        for (int i = 0; i < 4; ++i) {
            const int r = r0 + ty4 + i;
            const int c0 = col0 + tx4;
            ushort4 u;
            u.x = f2bf(acc[i][0] + bias[c0 + 0]);
            u.y = f2bf(acc[i][1] + bias[c0 + 1]);
            u.z = f2bf(acc[i][2] + bias[c0 + 2]);
            u.w = f2bf(acc[i][3] + bias[c0 + 3]);
            *reinterpret_cast<ushort4*>(&Y[(size_t)r * F_DIM + c0]) = u;
        }
    } else {
        // V: scatter-store transposed.  Vt[b][f][s], s = r>>4, b = r&15.
        #pragma unroll
        for (int i = 0; i < 4; ++i) {
            const int r = r0 + ty4 + i;
            const int s = r >> 4;
            const int b = r & 15;
            #pragma unroll
            for (int j = 0; j < 4; ++j) {
                const int f = col0 + tx4 + j;
                Vtd[((size_t)b * F_DIM + f) * S_LEN + s] = f2bf(acc[i][j] + bias[f]);
            }
        }
    }
}

// ---------------------------------------------------------------------------
// Kernel 2: MFMA flash attention.  Block = 4 waves x 16 q-rows (64 q), one
// batch.  K tile [64][256] + Vt tile [256][64] in LDS, XOR-swizzled on 16B
// slots (slot ^= row&7).  Q in registers.  mfma_f32_16x16x32_bf16 layouts:
//   A: row=l&15, k=(l>>4)*8+j;  B: col=l&15, k same;  D: col=l&15, row=(l>>4)*4+r
// ---------------------------------------------------------------------------
__global__ __launch_bounds__(256) void attn_mfma_kernel(
    const ushort_t* __restrict__ Qd,
    const ushort_t* __restrict__ Kd,
    const ushort_t* __restrict__ Vtd,
    float* __restrict__ out)
{
    __shared__ ushort_t Ks[64 * 256];    // 32 KB, swizzled rows of 512B (32 slots)
    __shared__ ushort_t Vts[256 * 64];   // 32 KB, swizzled rows of 128B (8 slots)
    __shared__ short    Ps[4][16 * 64];  // 2 KB per wave (short: matches bf16x8 elem type)

    const int tid = threadIdx.x;
    const int w   = tid >> 6;
    const int l   = tid & 63;
    const int lo  = l & 15;
    const int hi  = l >> 4;
    const int b   = blockIdx.y;
    const int q0  = blockIdx.x * 64;
    const int qw  = q0 + w * 16;

    // ---- Q fragments in registers: lane supplies Q[qw+lo][c*32 + hi*8 .. +8]
    bf16x8 qf[8];
    {
        const ushort_t* qrow = &Qd[((size_t)(qw + lo) * B_SZ + b) * F_DIM + hi * 8];
        #pragma unroll
        for (int c = 0; c < 8; ++c)
            qf[c] = *reinterpret_cast<const bf16x8*>(&qrow[c * 32]);
    }

    f32x4 O[16];
    #pragma unroll
    for (int fs = 0; fs < 16; ++fs) O[fs] = (f32x4){0.f, 0.f, 0.f, 0.f};
    float m_run[4] = {-1e30f, -1e30f, -1e30f, -1e30f};
    float l_run[4] = {0.f, 0.f, 0.f, 0.f};

    const int kslot = tid & 31, krow0 = tid >> 5;   // K staging: 8 rows/pass
    const int vslot = tid & 7,  vrow0 = tid >> 3;   // Vt staging: 32 rows/pass

    for (int t0 = 0; t0 < S_LEN; t0 += 64) {
        __syncthreads();   // prior tile's LDS reads complete

        // ---- stage K tile (swizzled) ----
        #pragma unroll
        for (int p = 0; p < 8; ++p) {
            const int row = krow0 + p * 8;
            const uint4 d = *reinterpret_cast<const uint4*>(
                &Kd[((size_t)(t0 + row) * B_SZ + b) * F_DIM + kslot * 8]);
            *reinterpret_cast<uint4*>(&Ks[row * 256 + ((kslot ^ (row & 7)) * 8)]) = d;
        }
        // ---- stage Vt tile (swizzled) ----
        #pragma unroll
        for (int p = 0; p < 8; ++p) {
            const int row = vrow0 + p * 32;   // feature row 0..255
            const uint4 d = *reinterpret_cast<const uint4*>(
                &Vtd[((size_t)b * F_DIM + row) * S_LEN + t0 + vslot * 8]);
            *reinterpret_cast<uint4*>(&Vts[row * 64 + ((vslot ^ (row & 7)) * 8)]) = d;
        }
        __syncthreads();

        // ---- QK^T: sc[ks] covers keys ks*16..+16 for this wave's 16 q-rows
        f32x4 sc[4];
        #pragma unroll
        for (int ks = 0; ks < 4; ++ks) sc[ks] = (f32x4){0.f, 0.f, 0.f, 0.f};
        #pragma unroll
        for (int ks = 0; ks < 4; ++ks) {
            const int krow = ks * 16 + lo;
            const ushort_t* kbase = &Ks[krow * 256];
            const int rx = krow & 7;
            #pragma unroll
            for (int c = 0; c < 8; ++c) {
                const bf16x8 kf = *reinterpret_cast<const bf16x8*>(
                    &kbase[((c * 4 + hi) ^ rx) * 8]);
                sc[ks] = __builtin_amdgcn_mfma_f32_16x16x32_bf16(qf[c], kf, sc[ks], 0, 0, 0);
            }
        }

        // ---- online softmax (rows = hi*4+r; reduce over keys: regs + lo-lanes)
        float fac[4];
        #pragma unroll
        for (int r = 0; r < 4; ++r) {
            float s0 = sc[0][r] * 0.0625f, s1 = sc[1][r] * 0.0625f;
            float s2 = sc[2][r] * 0.0625f, s3 = sc[3][r] * 0.0625f;
            float mt = fmaxf(fmaxf(s0, s1), fmaxf(s2, s3));
            mt = fmaxf(mt, __shfl_xor(mt, 1));
            mt = fmaxf(mt, __shfl_xor(mt, 2));
            mt = fmaxf(mt, __shfl_xor(mt, 4));
            mt = fmaxf(mt, __shfl_xor(mt, 8));
            const float mn = fmaxf(m_run[r], mt);
            fac[r] = __expf(m_run[r] - mn);
            m_run[r] = mn;
            const float p0 = __expf(s0 - mn), p1 = __expf(s1 - mn);
            const float p2 = __expf(s2 - mn), p3 = __expf(s3 - mn);
            float ps = (p0 + p1) + (p2 + p3);
            ps += __shfl_xor(ps, 1);
            ps += __shfl_xor(ps, 2);
            ps += __shfl_xor(ps, 4);
            ps += __shfl_xor(ps, 8);
            l_run[r] = l_run[r] * fac[r] + ps;
            // write P row (bf16, swizzled): row = hi*4+r, col = ks*16+lo
            const int row = hi * 4 + r;
            const int rx  = (row & 7) << 4;
            short* pw = &Ps[w][0];
            pw[(row * 128 + (((0 << 5) + (lo << 1)) ^ rx)) >> 1] = (short)f2bf(p0);
            pw[(row * 128 + (((1 << 5) + (lo << 1)) ^ rx)) >> 1] = (short)f2bf(p1);
            pw[(row * 128 + (((2 << 5) + (lo << 1)) ^ rx)) >> 1] = (short)f2bf(p2);
            pw[(row * 128 + (((3 << 5) + (lo << 1)) ^ rx)) >> 1] = (short)f2bf(p3);
        }

        // ---- rescale O by fac[r]  (O row mapping matches D: row = hi*4+r)
        #pragma unroll
        for (int fs = 0; fs < 16; ++fs) {
            O[fs][0] *= fac[0]; O[fs][1] *= fac[1];
            O[fs][2] *= fac[2]; O[fs][3] *= fac[3];
        }

        // ---- read P back as A-fragments (same wave; compiler orders LDS ops)
        bf16x8 pf[2];
        {
            const int prow = lo;
            const int rx = prow & 7;
            const short* pb = &Ps[w][prow * 64];
            pf[0] = *reinterpret_cast<const bf16x8*>(&pb[((0 * 4 + hi) ^ rx) * 8]);
            pf[1] = *reinterpret_cast<const bf16x8*>(&pb[((1 * 4 + hi) ^ rx) * 8]);
        }

        // ---- PV: O[fs] += P[16q x 64keys] . Vt-as-B[keys x 16f]
        #pragma unroll
        for (int fs = 0; fs < 16; ++fs) {
            const int vrow = fs * 16 + lo;
            const ushort_t* vbase = &Vts[vrow * 64];
            const int rx = vrow & 7;
            {
                const bf16x8 vf = *reinterpret_cast<const bf16x8*>(&vbase[((0 + hi) ^ rx) * 8]);
                O[fs] = __builtin_amdgcn_mfma_f32_16x16x32_bf16(pf[0], vf, O[fs], 0, 0, 0);
            }
            {
                const bf16x8 vf = *reinterpret_cast<const bf16x8*>(&vbase[((4 + hi) ^ rx) * 8]);
                O[fs] = __builtin_amdgcn_mfma_f32_16x16x32_bf16(pf[1], vf, O[fs], 0, 0, 0);
            }
        }
    }

    // ---- normalize + store: out[(qw + hi*4 + r)*B + b][fs*16 + lo]
    float inv[4];
    #pragma unroll
    for (int r = 0; r < 4; ++r) inv[r] = 1.0f / l_run[r];
    #pragma unroll
    for (int r = 0; r < 4; ++r) {
        const size_t rbase = ((size_t)(qw + hi * 4 + r) * B_SZ + b) * F_DIM + lo;
        #pragma unroll
        for (int fs = 0; fs < 16; ++fs)
            out[rbase + fs * 16] = O[fs][r] * inv[r];
    }
}

extern "C" void kernel_launch(void* const* d_in, const int* in_sizes, int n_in,
                              void* d_out, int out_size, void* d_ws, size_t ws_size,
                              hipStream_t stream) {
    const float* x  = (const float*)d_in[0];
    const float* Wq = (const float*)d_in[1];
    const float* bq = (const float*)d_in[2];
    const float* Wk = (const float*)d_in[3];
    const float* bk = (const float*)d_in[4];
    const float* Wv = (const float*)d_in[5];
    const float* bv = (const float*)d_in[6];
    float* out = (float*)d_out;

    const size_t elems = (size_t)NROWS * F_DIM;          // 8.4M per tensor
    ushort_t* Qd  = (ushort_t*)d_ws;
    ushort_t* Kd  = Qd + elems;
    ushort_t* Vtd = Kd + elems;                          // 50.33 MB total (== R2)

    hipLaunchKernelGGL(qkv_proj_kernel, dim3(512, 12), dim3(256), 0, stream,
                       x, Wq, bq, Wk, bk, Wv, bv, Qd, Kd, Vtd);
    hipLaunchKernelGGL(attn_mfma_kernel, dim3(S_LEN / 64, B_SZ), dim3(256), 0, stream,
                       Qd, Kd, Vtd, out);
}

// Round 5
// 461.708 us; speedup vs baseline: 4.4342x; 1.2371x over previous
//
#include <hip/hip_runtime.h>
#include <hip/hip_bf16.h>

#define S_LEN 2048
#define B_SZ  16
#define F_DIM 256
#define NROWS (S_LEN * B_SZ)   // 32768

typedef unsigned short ushort_t;
typedef unsigned int   uint_t;
typedef __attribute__((ext_vector_type(8))) short bf16x8;
typedef __attribute__((ext_vector_type(4))) float f32x4;

__device__ __forceinline__ ushort_t f2bf(float f) {
    uint_t x = __float_as_uint(f);
    uint_t r = x + 0x7fffu + ((x >> 16) & 1u);
    return (ushort_t)(r >> 16);
}

__device__ __forceinline__ bf16x8 pack8(float4 a, float4 b) {
    union { bf16x8 v; __hip_bfloat162 h[4]; } u;
    u.h[0] = __float22bfloat162_rn(make_float2(a.x, a.y));
    u.h[1] = __float22bfloat162_rn(make_float2(a.z, a.w));
    u.h[2] = __float22bfloat162_rn(make_float2(b.x, b.y));
    u.h[3] = __float22bfloat162_rn(make_float2(b.z, b.w));
    return u.v;
}

// ---------------------------------------------------------------------------
// Kernel 1: MFMA QKV projection.  Block = 256 thr (4 waves) x 32 rows of x.
// x tile staged ONCE as bf16 in swizzled LDS (R4 K-staging pattern); Q, K, V
// computed from it in 3 phases.  W -> B-frags in registers via packed cvt.
// Wave w owns cols w*64..w*64+63.  Per phase: 2m x 4ks x 8c MFMA.
// Q/K stored row-major bf16; V stored transposed Vt[b][f][s] (R4-proven
// scatter).  ws = 3 x 16.77 MB (proven size).
// ---------------------------------------------------------------------------
__global__ __launch_bounds__(256) void qkv_proj_mfma_kernel(
    const float* __restrict__ x,
    const float* __restrict__ Wq, const float* __restrict__ bq,
    const float* __restrict__ Wk, const float* __restrict__ bk,
    const float* __restrict__ Wv, const float* __restrict__ bv,
    ushort_t* __restrict__ Qd, ushort_t* __restrict__ Kd, ushort_t* __restrict__ Vtd)
{
    __shared__ ushort_t Xs[32 * 256];   // 16 KB, swizzled rows of 512B (32 slots)

    const int tid = threadIdx.x;
    const int w   = tid >> 6;
    const int l   = tid & 63;
    const int lo  = l & 15;
    const int hi  = l >> 4;
    const int r0  = blockIdx.x * 32;
    const int wcol0 = w * 64;

    // ---- stage x tile: fp32 -> bf16, swizzled (slot ^= row&7 on 16B slots)
    {
        const int row   = tid >> 3;        // 0..31
        const int slot0 = (tid & 7) * 4;   // 4 slots of 8 elems each
        const float* xrow = &x[(size_t)(r0 + row) * F_DIM];
        #pragma unroll
        for (int c = 0; c < 4; ++c) {
            const int slot = slot0 + c;
            const float4 f0 = *reinterpret_cast<const float4*>(&xrow[slot * 8 + 0]);
            const float4 f1 = *reinterpret_cast<const float4*>(&xrow[slot * 8 + 4]);
            *reinterpret_cast<bf16x8*>(&Xs[row * 256 + ((slot ^ (row & 7)) * 8)]) = pack8(f0, f1);
        }
    }
    __syncthreads();

    const float* Wmat[3]  = {Wq, Wk, Wv};
    const float* Bias[3]  = {bq, bk, bv};

    for (int mat = 0; mat < 3; ++mat) {
        const float* W    = Wmat[mat];
        const float* bias = Bias[mat];

        f32x4 acc[2][4];
        #pragma unroll
        for (int m = 0; m < 2; ++m)
            #pragma unroll
            for (int ks = 0; ks < 4; ++ks) acc[m][ks] = (f32x4){0.f, 0.f, 0.f, 0.f};

        #pragma unroll
        for (int ks = 0; ks < 4; ++ks) {
            // ---- W B-frags for this 16-col subtile: col=lo, k = c*32+hi*8+j
            bf16x8 wf[8];
            {
                const float* wrow = &W[(size_t)(wcol0 + ks * 16 + lo) * F_DIM + hi * 8];
                #pragma unroll
                for (int c = 0; c < 8; ++c) {
                    const float4 f0 = *reinterpret_cast<const float4*>(&wrow[c * 32 + 0]);
                    const float4 f1 = *reinterpret_cast<const float4*>(&wrow[c * 32 + 4]);
                    wf[c] = pack8(f0, f1);
                }
            }
            #pragma unroll
            for (int m = 0; m < 2; ++m) {
                const int arow = m * 16 + lo;
                const ushort_t* abase = &Xs[arow * 256];
                const int rx = arow & 7;
                #pragma unroll
                for (int c = 0; c < 8; ++c) {
                    const bf16x8 af = *reinterpret_cast<const bf16x8*>(
                        &abase[((c * 4 + hi) ^ rx) * 8]);
                    acc[m][ks] = __builtin_amdgcn_mfma_f32_16x16x32_bf16(af, wf[c], acc[m][ks], 0, 0, 0);
                }
            }
        }

        // ---- epilogue: bias + store.  D: col=lo (within subtile), row=hi*4+r
        if (mat < 2) {
            ushort_t* Y = (mat == 0) ? Qd : Kd;
            #pragma unroll
            for (int ks = 0; ks < 4; ++ks) {
                const int col = wcol0 + ks * 16 + lo;
                const float bv_ = bias[col];
                #pragma unroll
                for (int m = 0; m < 2; ++m) {
                    #pragma unroll
                    for (int r = 0; r < 4; ++r) {
                        const int row = r0 + m * 16 + hi * 4 + r;
                        Y[(size_t)row * F_DIM + col] = f2bf(acc[m][ks][r] + bv_);
                    }
                }
            }
        } else {
            // V: scatter transposed.  Vt[b][f][s], s = row>>4, b = row&15.
            #pragma unroll
            for (int ks = 0; ks < 4; ++ks) {
                const int f = wcol0 + ks * 16 + lo;
                const float bv_ = bias[f];
                #pragma unroll
                for (int m = 0; m < 2; ++m) {
                    #pragma unroll
                    for (int r = 0; r < 4; ++r) {
                        const int row = r0 + m * 16 + hi * 4 + r;
                        const int s = row >> 4;
                        const int b = row & 15;
                        Vtd[((size_t)b * F_DIM + f) * S_LEN + s] = f2bf(acc[m][ks][r] + bv_);
                    }
                }
            }
        }
    }
}

// ---------------------------------------------------------------------------
// Kernel 2: MFMA flash attention (unchanged from R4).  Block = 4 waves x 16
// q-rows (64 q), one batch.  K tile [64][256] + Vt tile [256][64] in LDS,
// XOR-swizzled on 16B slots (slot ^= row&7).  Q in registers.
//   A: row=l&15, k=(l>>4)*8+j;  B: col=l&15, k same;  D: col=l&15, row=(l>>4)*4+r
// ---------------------------------------------------------------------------
__global__ __launch_bounds__(256) void attn_mfma_kernel(
    const ushort_t* __restrict__ Qd,
    const ushort_t* __restrict__ Kd,
    const ushort_t* __restrict__ Vtd,
    float* __restrict__ out)
{
    __shared__ ushort_t Ks[64 * 256];    // 32 KB
    __shared__ ushort_t Vts[256 * 64];   // 32 KB
    __shared__ short    Ps[4][16 * 64];  // 2 KB per wave

    const int tid = threadIdx.x;
    const int w   = tid >> 6;
    const int l   = tid & 63;
    const int lo  = l & 15;
    const int hi  = l >> 4;
    const int b   = blockIdx.y;
    const int q0  = blockIdx.x * 64;
    const int qw  = q0 + w * 16;

    bf16x8 qf[8];
    {
        const ushort_t* qrow = &Qd[((size_t)(qw + lo) * B_SZ + b) * F_DIM + hi * 8];
        #pragma unroll
        for (int c = 0; c < 8; ++c)
            qf[c] = *reinterpret_cast<const bf16x8*>(&qrow[c * 32]);
    }

    f32x4 O[16];
    #pragma unroll
    for (int fs = 0; fs < 16; ++fs) O[fs] = (f32x4){0.f, 0.f, 0.f, 0.f};
    float m_run[4] = {-1e30f, -1e30f, -1e30f, -1e30f};
    float l_run[4] = {0.f, 0.f, 0.f, 0.f};

    const int kslot = tid & 31, krow0 = tid >> 5;
    const int vslot = tid & 7,  vrow0 = tid >> 3;

    for (int t0 = 0; t0 < S_LEN; t0 += 64) {
        __syncthreads();

        #pragma unroll
        for (int p = 0; p < 8; ++p) {
            const int row = krow0 + p * 8;
            const uint4 d = *reinterpret_cast<const uint4*>(
                &Kd[((size_t)(t0 + row) * B_SZ + b) * F_DIM + kslot * 8]);
            *reinterpret_cast<uint4*>(&Ks[row * 256 + ((kslot ^ (row & 7)) * 8)]) = d;
        }
        #pragma unroll
        for (int p = 0; p < 8; ++p) {
            const int row = vrow0 + p * 32;
            const uint4 d = *reinterpret_cast<const uint4*>(
                &Vtd[((size_t)b * F_DIM + row) * S_LEN + t0 + vslot * 8]);
            *reinterpret_cast<uint4*>(&Vts[row * 64 + ((vslot ^ (row & 7)) * 8)]) = d;
        }
        __syncthreads();

        f32x4 sc[4];
        #pragma unroll
        for (int ks = 0; ks < 4; ++ks) sc[ks] = (f32x4){0.f, 0.f, 0.f, 0.f};
        #pragma unroll
        for (int ks = 0; ks < 4; ++ks) {
            const int krow = ks * 16 + lo;
            const ushort_t* kbase = &Ks[krow * 256];
            const int rx = krow & 7;
            #pragma unroll
            for (int c = 0; c < 8; ++c) {
                const bf16x8 kf = *reinterpret_cast<const bf16x8*>(
                    &kbase[((c * 4 + hi) ^ rx) * 8]);
                sc[ks] = __builtin_amdgcn_mfma_f32_16x16x32_bf16(qf[c], kf, sc[ks], 0, 0, 0);
            }
        }

        float fac[4];
        #pragma unroll
        for (int r = 0; r < 4; ++r) {
            float s0 = sc[0][r] * 0.0625f, s1 = sc[1][r] * 0.0625f;
            float s2 = sc[2][r] * 0.0625f, s3 = sc[3][r] * 0.0625f;
            float mt = fmaxf(fmaxf(s0, s1), fmaxf(s2, s3));
            mt = fmaxf(mt, __shfl_xor(mt, 1));
            mt = fmaxf(mt, __shfl_xor(mt, 2));
            mt = fmaxf(mt, __shfl_xor(mt, 4));
            mt = fmaxf(mt, __shfl_xor(mt, 8));
            const float mn = fmaxf(m_run[r], mt);
            fac[r] = __expf(m_run[r] - mn);
            m_run[r] = mn;
            const float p0 = __expf(s0 - mn), p1 = __expf(s1 - mn);
            const float p2 = __expf(s2 - mn), p3 = __expf(s3 - mn);
            float ps = (p0 + p1) + (p2 + p3);
            ps += __shfl_xor(ps, 1);
            ps += __shfl_xor(ps, 2);
            ps += __shfl_xor(ps, 4);
            ps += __shfl_xor(ps, 8);
            l_run[r] = l_run[r] * fac[r] + ps;
            const int row = hi * 4 + r;
            const int rx  = (row & 7) << 4;
            short* pw = &Ps[w][0];
            pw[(row * 128 + (((0 << 5) + (lo << 1)) ^ rx)) >> 1] = (short)f2bf(p0);
            pw[(row * 128 + (((1 << 5) + (lo << 1)) ^ rx)) >> 1] = (short)f2bf(p1);
            pw[(row * 128 + (((2 << 5) + (lo << 1)) ^ rx)) >> 1] = (short)f2bf(p2);
            pw[(row * 128 + (((3 << 5) + (lo << 1)) ^ rx)) >> 1] = (short)f2bf(p3);
        }

        #pragma unroll
        for (int fs = 0; fs < 16; ++fs) {
            O[fs][0] *= fac[0]; O[fs][1] *= fac[1];
            O[fs][2] *= fac[2]; O[fs][3] *= fac[3];
        }

        bf16x8 pf[2];
        {
            const int prow = lo;
            const int rx = prow & 7;
            const short* pb = &Ps[w][prow * 64];
            pf[0] = *reinterpret_cast<const bf16x8*>(&pb[((0 * 4 + hi) ^ rx) * 8]);
            pf[1] = *reinterpret_cast<const bf16x8*>(&pb[((1 * 4 + hi) ^ rx) * 8]);
        }

        #pragma unroll
        for (int fs = 0; fs < 16; ++fs) {
            const int vrow = fs * 16 + lo;
            const ushort_t* vbase = &Vts[vrow * 64];
            const int rx = vrow & 7;
            {
                const bf16x8 vf = *reinterpret_cast<const bf16x8*>(&vbase[((0 + hi) ^ rx) * 8]);
                O[fs] = __builtin_amdgcn_mfma_f32_16x16x32_bf16(pf[0], vf, O[fs], 0, 0, 0);
            }
            {
                const bf16x8 vf = *reinterpret_cast<const bf16x8*>(&vbase[((4 + hi) ^ rx) * 8]);
                O[fs] = __builtin_amdgcn_mfma_f32_16x16x32_bf16(pf[1], vf, O[fs], 0, 0, 0);
            }
        }
    }

    float inv[4];
    #pragma unroll
    for (int r = 0; r < 4; ++r) inv[r] = 1.0f / l_run[r];
    #pragma unroll
    for (int r = 0; r < 4; ++r) {
        const size_t rbase = ((size_t)(qw + hi * 4 + r) * B_SZ + b) * F_DIM + lo;
        #pragma unroll
        for (int fs = 0; fs < 16; ++fs)
            out[rbase + fs * 16] = O[fs][r] * inv[r];
    }
}

extern "C" void kernel_launch(void* const* d_in, const int* in_sizes, int n_in,
                              void* d_out, int out_size, void* d_ws, size_t ws_size,
                              hipStream_t stream) {
    const float* x  = (const float*)d_in[0];
    const float* Wq = (const float*)d_in[1];
    const float* bq = (const float*)d_in[2];
    const float* Wk = (const float*)d_in[3];
    const float* bk = (const float*)d_in[4];
    const float* Wv = (const float*)d_in[5];
    const float* bv = (const float*)d_in[6];
    float* out = (float*)d_out;

    const size_t elems = (size_t)NROWS * F_DIM;          // 8.4M per tensor
    ushort_t* Qd  = (ushort_t*)d_ws;
    ushort_t* Kd  = Qd + elems;
    ushort_t* Vtd = Kd + elems;                          // 50.33 MB total (proven)

    hipLaunchKernelGGL(qkv_proj_mfma_kernel, dim3(NROWS / 32), dim3(256), 0, stream,
                       x, Wq, bq, Wk, bk, Wv, bv, Qd, Kd, Vtd);
    hipLaunchKernelGGL(attn_mfma_kernel, dim3(S_LEN / 64, B_SZ), dim3(256), 0, stream,
                       Qd, Kd, Vtd, out);
}